// Round 15
// baseline (139.807 us; speedup 1.0000x reference)
//
#include <hip/hip_runtime.h>

typedef __attribute__((ext_vector_type(8))) short short8;
typedef __attribute__((ext_vector_type(4))) float f32x4;
typedef __attribute__((ext_vector_type(4))) unsigned int u32x4;
typedef unsigned short ushort_t;

constexpr int B   = 4;
constexpr int C   = 256;
constexpr int H   = 64;
constexpr int W   = 64;
constexpr int HW  = H * W;          // 4096
constexpr int OCH = 256;
constexpr int KT  = 9 * C;          // 2304, k order: k = tap*256 + c
constexpr int NHS = KT / 32;        // 72 half-steps (MFMA K=32)

__device__ __forceinline__ ushort_t f2bf(float f) {
    unsigned u = __float_as_uint(f);
    u += 0x7FFF + ((u >> 16) & 1);      // RNE
    return (ushort_t)(u >> 16);
}

// Barrier that does NOT drain vmcnt: LDS writes are made visible
// (lgkmcnt(0)), but in-register global loads stay in flight across it.
__device__ __forceinline__ void block_sync_lds() {
    asm volatile("s_waitcnt lgkmcnt(0)" ::: "memory");
    __builtin_amdgcn_s_barrier();
    asm volatile("" ::: "memory");
}

// ---------------------------------------------------------------------------
// K0: prep = transpose (blocks 0..1023) + weight packing (blocks 1024..1347).
// Transpose: xt[b][y][x][c] (bf16) <- x[b][c][y][x] (f32); b<2 -> xt01 (ws),
// b>=2 -> xtD (d_out batch-0 scratch).  Pack: validated rounds 2-14.
// ---------------------------------------------------------------------------
__global__ __launch_bounds__(256) void prep_all(
    const float* __restrict__ x, const float* __restrict__ w_def,
    const float* __restrict__ w_off, ushort_t* __restrict__ xt01,
    ushort_t* __restrict__ xtD, ushort_t* __restrict__ wPack,
    ushort_t* __restrict__ wOffA)
{
    __shared__ float sT[64][65];
    int blk = blockIdx.x;
    if (blk < 1024) {
        int cg  = blk & 3;               // channel group of 64
        int y   = (blk >> 2) & 63;
        int b   = blk >> 8;              // 0..3
        int t   = threadIdx.x;
        int col = t & 63, r4 = t >> 6;

        const float* xp = x + (((size_t)b * C + cg * 64) * H + y) * W;
        #pragma unroll
        for (int i = 0; i < 16; ++i) {
            int cl = i * 4 + r4;
            sT[cl][col] = xp[(size_t)cl * HW + col];
        }
        __syncthreads();
        ushort_t* base = (b < 2) ? (xt01 + (size_t)b * HW * C)
                                 : (xtD + (size_t)(b - 2) * HW * C);
        ushort_t* op = base + ((size_t)y * W) * C + cg * 64;
        #pragma unroll
        for (int i = 0; i < 16; ++i) {
            int xl = i * 4 + r4;
            op[(size_t)xl * C + col] = f2bf(sT[col][xl]);
        }
    } else {
        int tid = (blk - 1024) * 256 + threadIdx.x;   // [0, 82944)
        if (tid < NHS * 16 * 64) {
            int lane = tid & 63;
            int o = ((tid >> 6) & 15) * 16 + (lane & 15);
            int kbase = (tid >> 10) * 32 + (lane >> 4) * 8;
            union { ushort_t u[8]; short8 v; } pk;
            #pragma unroll
            for (int j = 0; j < 8; ++j) {
                int kidx = kbase + j;
                int c = kidx & 255, tap = kidx >> 8;
                pk.u[j] = f2bf(w_def[((size_t)o * C + c) * 9 + tap]);
            }
            *(short8*)(wPack + (size_t)tid * 8) = pk.v;
        } else {
            int t2 = tid - NHS * 16 * 64;             // [0, 9216)
            int lane = t2 & 63;
            int o = ((t2 >> 6) & 1) * 16 + (lane & 15);
            int kbase = (t2 >> 7) * 32 + (lane >> 4) * 8;
            union { ushort_t u[8]; short8 v; } pk;
            #pragma unroll
            for (int j = 0; j < 8; ++j) {
                int kidx = kbase + j;
                int c = kidx & 255, tap = kidx >> 8;
                pk.u[j] = (o < 18) ? f2bf(w_off[((size_t)o * C + c) * 9 + tap]) : (ushort_t)0;
            }
            *(short8*)(wOffA + (size_t)t2 * 8) = pk.v;
        }
    }
}

// ---------------------------------------------------------------------------
// K3: offset conv via MFMA (validated rounds 5-14).  Grid (b,ho) = 256.
// ---------------------------------------------------------------------------
__global__ __launch_bounds__(256) void offconv_all(
    const ushort_t* __restrict__ xt01, const ushort_t* __restrict__ xtD,
    const ushort_t* __restrict__ wOffA, float* __restrict__ offFull)
{
    int orig = blockIdx.x;
    int r = ((orig & 7) << 5) | (orig >> 3);   // XCD swizzle, 256 blocks
    int b = r >> 6, ho = r & 63;
    int tid = threadIdx.x;
    int lane = tid & 63, wv = tid >> 6;
    int px = wv * 16 + (lane & 15);
    int cseg = (lane >> 4) * 8;

    const ushort_t* xtb = (b < 2) ? (xt01 + (size_t)b * HW * C)
                                  : (xtD + (size_t)(b - 2) * HW * C);
    const short8* wA = (const short8*)wOffA;

    f32x4 acc[2];
    acc[0] = (f32x4){0.f, 0.f, 0.f, 0.f};
    acc[1] = (f32x4){0.f, 0.f, 0.f, 0.f};

    #pragma unroll 1
    for (int tap = 0; tap < 9; ++tap) {
        int ky = tap / 3, kx = tap - ky * 3;
        int y  = ho - 1 + ky;
        int xx = px - 1 + kx;
        bool ok = ((unsigned)y < 64u) && ((unsigned)xx < 64u);
        unsigned msk = ok ? 0xffffffffu : 0u;
        int yc = min(max(y, 0), 63), xc = min(max(xx, 0), 63);
        const ushort_t* srcb = xtb + (size_t)(yc * 64 + xc) * C + cseg;

        #pragma unroll
        for (int cs = 0; cs < 8; ++cs) {
            union { u32x4 u; short8 s; } bv;
            bv.u = *(const u32x4*)(srcb + cs * 32);
            bv.u[0] &= msk; bv.u[1] &= msk; bv.u[2] &= msk; bv.u[3] &= msk;
            int ks = tap * 8 + cs;
            short8 aF0 = wA[(size_t)ks * 128 + lane];
            short8 aF1 = wA[(size_t)ks * 128 + 64 + lane];
            acc[0] = __builtin_amdgcn_mfma_f32_16x16x32_bf16(aF0, bv.s, acc[0], 0, 0, 0);
            acc[1] = __builtin_amdgcn_mfma_f32_16x16x32_bf16(aF1, bv.s, acc[1], 0, 0, 0);
        }
    }

    #pragma unroll
    for (int gt = 0; gt < 2; ++gt) {
        #pragma unroll
        for (int j = 0; j < 4; ++j) {
            int oc = gt * 16 + (lane >> 4) * 4 + j;
            if (oc < 18)
                offFull[((size_t)b * 18 + oc) * HW + ho * 64 + px] = acc[gt][j];
        }
    }
}

// ---------------------------------------------------------------------------
// K4: bilinear sample + bf16 MFMA GEMM.  256o x 32px per block, 512 thr
// (8 waves, wave = 32o x 32px).  ONE barrier per tap: stage both 128-ch subs
// (8 x 16B coalesced loads, in-register blend, 32 B-frag slots), barrier,
// then 8 half-steps of MFMA with A-fragments double-buffered across taps.
// launch_bounds(512, 1): VGPR budget up to 256 -- the pipeline state
// (A0[16]+A1[16]=128 + L[8]=32 + acc) needs ~210; the r14 (512,2) variant
// capped at 128 and spilled 65 MB to scratch (the regression).
// 1 block/CU x 8 waves = same waves/CU as the proven r12 config.
// Grid (bl,ho,pxh) = 256 blocks/launch.
// ---------------------------------------------------------------------------
__global__ __launch_bounds__(512, 1) void deform_pair(
    const ushort_t* __restrict__ xtB, const float* __restrict__ offFull,
    const ushort_t* __restrict__ wPack, float* __restrict__ out, int pbase)
{
    __shared__ __align__(16) ushort_t sS[2][32][33][8]; // 33.8 KB (dbuf x 32 slots)
    __shared__ float sOff[18][32];                      // 2.3 KB
    __shared__ int   sBase[2][128];                     // run bases (dbuf)
    __shared__ float sWgt[2][32][4];                    // per-px nbr weights

    int orig = blockIdx.x;
    int r = ((orig & 7) << 5) | (orig >> 3);   // XCD swizzle, 256 blocks
    int bl = r >> 7, ho = (r >> 1) & 63, pxh = r & 1;
    int tid = threadIdx.x;
    int lane = tid & 63, wv = tid >> 6;        // 8 waves
    int chunk = tid & 15, rq = (tid >> 4) & 31;  // staging: pixel rq, chunk

    const ushort_t* xtb = xtB + (size_t)bl * HW * C;
    int b = pbase + bl;

    // this row's offsets for our px half
    for (int idx = tid; idx < 18 * 32; idx += 512) {
        int oc = idx >> 5, p2 = idx & 31;
        sOff[oc][p2] = offFull[((size_t)b * 18 + oc) * HW + ho * 64 + pxh * 32 + p2];
    }
    __syncthreads();

    f32x4 acc2[2][2];
    #pragma unroll
    for (int i = 0; i < 2; ++i)
        #pragma unroll
        for (int j = 0; j < 2; ++j) acc2[i][j] = (f32x4){0.f, 0.f, 0.f, 0.f};

    // run bases + per-pixel neighbor weights (validity folded in), dbuf by tap
    auto computeBase = [&](int tap, int buf) {
        if (tid < 128) {
            int n = tid >> 5, q = tid & 31;
            int ky = tap / 3, kx = tap - ky * 3;
            float offy = sOff[2 * tap][q];
            float offx = sOff[2 * tap + 1][q];
            float py  = offy + (float)(ho - 1 + ky);
            float pxf = offx + (float)(pxh * 32 + q - 1 + kx);
            float y0f = floorf(py), x0f = floorf(pxf);
            float wy1 = py - y0f, wx1 = pxf - x0f;
            int y0 = (int)y0f, x0 = (int)x0f;
            int dy = n >> 1, dx = n & 1;
            int yy = y0 + dy, xx = x0 + dx;
            float wn = (dy ? wy1 : (1.f - wy1)) * (dx ? wx1 : (1.f - wx1));
            wn *= (((unsigned)yy < 64u) ? 1.f : 0.f) * (((unsigned)xx < 64u) ? 1.f : 0.f);
            int yc = min(max(yy, 0), 63), xc = min(max(xx, 0), 63);
            sBase[buf][tid] = (yc * 64 + xc) * C;
            sWgt[buf][q][n] = wn;
        }
    };

    auto loadBases = [&](int buf, int* rb) {
        #pragma unroll
        for (int n = 0; n < 4; ++n) rb[n] = sBase[buf][n * 32 + rq];
    };

    // coalesced: 8 x 16B, neighbor n of pixel rq, subs 0 and 1
    auto issueBoth = [&](const int* rb, u32x4* L) {
        #pragma unroll
        for (int n = 0; n < 4; ++n) {
            const ushort_t* p0 = xtb + rb[n] + chunk * 8;
            L[n]     = *(const u32x4*)p0;
            L[4 + n] = *(const u32x4*)(p0 + 128);
        }
    };

    // in-register blend of both subs: sub0 -> slot chunk, sub1 -> slot 16+chunk
    auto blendBoth = [&](const u32x4* L, const float* w, int p) {
        #pragma unroll
        for (int s = 0; s < 2; ++s) {
            unsigned pk[4];
            #pragma unroll
            for (int j = 0; j < 4; ++j) {
                float f0l = __uint_as_float(L[s * 4 + 0][j] << 16);
                float f0h = __uint_as_float(L[s * 4 + 0][j] & 0xffff0000u);
                float f1l = __uint_as_float(L[s * 4 + 1][j] << 16);
                float f1h = __uint_as_float(L[s * 4 + 1][j] & 0xffff0000u);
                float f2l = __uint_as_float(L[s * 4 + 2][j] << 16);
                float f2h = __uint_as_float(L[s * 4 + 2][j] & 0xffff0000u);
                float f3l = __uint_as_float(L[s * 4 + 3][j] << 16);
                float f3h = __uint_as_float(L[s * 4 + 3][j] & 0xffff0000u);
                float lo = fmaf(w[0], f0l, fmaf(w[1], f1l, fmaf(w[2], f2l, w[3] * f3l)));
                float hi = fmaf(w[0], f0h, fmaf(w[1], f1h, fmaf(w[2], f2h, w[3] * f3h)));
                asm("v_cvt_pk_bf16_f32 %0, %1, %2" : "=v"(pk[j]) : "v"(lo), "v"(hi));
            }
            u32x4 wvec = (u32x4){pk[0], pk[1], pk[2], pk[3]};
            *(u32x4*)&sS[p][s * 16 + chunk][rq][0] = wvec;
        }
    };

    int gt0 = wv * 2;
    const short8* wpB = (const short8*)wPack;

    auto loadA = [&](int tap, short8* A) {   // 16 A-frags for a full tap
        #pragma unroll
        for (int h = 0; h < 8; ++h) {
            size_t an = ((size_t)(tap * 8 + h) * 16 + gt0) * 64 + lane;
            A[2 * h]     = wpB[an];
            A[2 * h + 1] = wpB[an + 64];
        }
    };

    auto mfmaPhase = [&](const short8* A, int p) {
        #pragma unroll
        for (int h = 0; h < 8; ++h) {
            #pragma unroll
            for (int pt = 0; pt < 2; ++pt) {
                short8 bF = *(const short8*)&sS[p][h * 4 + (lane >> 4)][pt * 16 + (lane & 15)][0];
                acc2[0][pt] = __builtin_amdgcn_mfma_f32_16x16x32_bf16(A[2 * h],     bF, acc2[0][pt], 0, 0, 0);
                acc2[1][pt] = __builtin_amdgcn_mfma_f32_16x16x32_bf16(A[2 * h + 1], bF, acc2[1][pt], 0, 0, 0);
            }
        }
    };

    u32x4 L[8];
    short8 A0[16], A1[16];

    // prologue
    computeBase(0, 0);
    block_sync_lds();
    {
        int rb0[4];
        loadBases(0, rb0);
        issueBoth(rb0, L);
    }
    loadA(0, A0);

    int p = 0;
    #pragma unroll 1
    for (int tap = 0; tap < 9; ++tap) {
        float wcur[4];
        *(float4*)&wcur[0] = *(const float4*)&sWgt[tap & 1][rq][0];
        if (tap < 8) computeBase(tap + 1, (tap + 1) & 1);

        blendBoth(L, wcur, p);
        block_sync_lds();              // publishes sS[p] + next tap's bases/wgts

        int rb[4];
        if (tap < 8) { loadBases((tap + 1) & 1, rb); issueBoth(rb, L); }

        if ((tap & 1) == 0) {
            if (tap < 8) loadA(tap + 1, A1);   // prefetch under MFMA phase
            mfmaPhase(A0, p);
        } else {
            if (tap < 8) loadA(tap + 1, A0);
            mfmaPhase(A1, p);
        }
        p ^= 1;
    }

    // epilogue: D[row=(l>>4)*4+j][col=l&15]
    #pragma unroll
    for (int ot = 0; ot < 2; ++ot) {
        int o = wv * 32 + ot * 16 + (lane >> 4) * 4;
        #pragma unroll
        for (int pt = 0; pt < 2; ++pt) {
            int pxx = pxh * 32 + pt * 16 + (lane & 15);
            #pragma unroll
            for (int j = 0; j < 4; ++j)
                out[(((size_t)b * OCH + (o + j)) * H + ho) * W + pxx] = acc2[ot][pt][j];
        }
    }
}

// ---------------------------------------------------------------------------
extern "C" void kernel_launch(void* const* d_in, const int* in_sizes, int n_in,
                              void* d_out, int out_size, void* d_ws, size_t ws_size,
                              hipStream_t stream)
{
    const float* x     = (const float*)d_in[0];
    const float* w_off = (const float*)d_in[1];
    const float* w_def = (const float*)d_in[2];
    float* out = (float*)d_out;

    // ws: xt01[4.19MB] | wPack[1.18MB] | wOffA[147KB] | offFull[1.18MB]
    // total 6,701,056 B (proven).  xt23 lives in d_out's batch-0 region:
    // written by prep, read by offconv + deform(pbase=2) (writes out[b2,b3]
    // only), then overwritten by deform(pbase=0)'s out[b0] stores.
    ushort_t* xt01    = (ushort_t*)d_ws;
    ushort_t* wPack   = xt01 + (size_t)2 * HW * C;
    ushort_t* wOffA   = wPack + (size_t)NHS * 16 * 64 * 8;
    float*    offFull = (float*)(wOffA + (size_t)NHS * 2 * 64 * 8);
    ushort_t* xtD     = (ushort_t*)d_out;   // batch 2,3 xt scratch

    prep_all<<<1348, 256, 0, stream>>>(x, w_def, w_off, xt01, xtD, wPack, wOffA);
    offconv_all<<<256, 256, 0, stream>>>(xt01, xtD, wOffA, offFull);
    deform_pair<<<256, 512, 0, stream>>>(xtD, offFull, wPack, out, 2);
    deform_pair<<<256, 512, 0, stream>>>(xt01, offFull, wPack, out, 0);
}

// Round 17
// 94.460 us; speedup vs baseline: 1.4801x; 1.4801x over previous
//
#include <hip/hip_runtime.h>

typedef __attribute__((ext_vector_type(8))) short short8;
typedef __attribute__((ext_vector_type(4))) float f32x4;
typedef __attribute__((ext_vector_type(4))) unsigned int u32x4;
typedef unsigned short ushort_t;

constexpr int B   = 4;
constexpr int C   = 256;
constexpr int H   = 64;
constexpr int W   = 64;
constexpr int HW  = H * W;          // 4096
constexpr int OCH = 256;
constexpr int KT  = 9 * C;          // 2304, k order: k = tap*256 + c
constexpr int NHS = KT / 32;        // 72 half-steps (MFMA K=32)

__device__ __forceinline__ ushort_t f2bf(float f) {
    unsigned u = __float_as_uint(f);
    u += 0x7FFF + ((u >> 16) & 1);      // RNE
    return (ushort_t)(u >> 16);
}

// Barrier that does NOT drain vmcnt: LDS writes are made visible
// (lgkmcnt(0)), but in-register global loads stay in flight across it.
__device__ __forceinline__ void block_sync_lds() {
    asm volatile("s_waitcnt lgkmcnt(0)" ::: "memory");
    __builtin_amdgcn_s_barrier();
    asm volatile("" ::: "memory");
}

// ---------------------------------------------------------------------------
// K0: prep = transpose (blocks 0..1023) + weight packing (blocks 1024..1347).
// Transpose: xt[b][y][x][c] (bf16) <- x[b][c][y][x] (f32); b<2 -> xt01 (ws),
// b>=2 -> xtD (d_out batch-0 scratch).  Pack: validated rounds 2-13.
// ---------------------------------------------------------------------------
__global__ __launch_bounds__(256) void prep_all(
    const float* __restrict__ x, const float* __restrict__ w_def,
    const float* __restrict__ w_off, ushort_t* __restrict__ xt01,
    ushort_t* __restrict__ xtD, ushort_t* __restrict__ wPack,
    ushort_t* __restrict__ wOffA)
{
    __shared__ float sT[64][65];
    int blk = blockIdx.x;
    if (blk < 1024) {
        int cg  = blk & 3;               // channel group of 64
        int y   = (blk >> 2) & 63;
        int b   = blk >> 8;              // 0..3
        int t   = threadIdx.x;
        int col = t & 63, r4 = t >> 6;

        const float* xp = x + (((size_t)b * C + cg * 64) * H + y) * W;
        #pragma unroll
        for (int i = 0; i < 16; ++i) {
            int cl = i * 4 + r4;
            sT[cl][col] = xp[(size_t)cl * HW + col];
        }
        __syncthreads();
        ushort_t* base = (b < 2) ? (xt01 + (size_t)b * HW * C)
                                 : (xtD + (size_t)(b - 2) * HW * C);
        ushort_t* op = base + ((size_t)y * W) * C + cg * 64;
        #pragma unroll
        for (int i = 0; i < 16; ++i) {
            int xl = i * 4 + r4;
            op[(size_t)xl * C + col] = f2bf(sT[col][xl]);
        }
    } else {
        int tid = (blk - 1024) * 256 + threadIdx.x;   // [0, 82944)
        if (tid < NHS * 16 * 64) {
            int lane = tid & 63;
            int o = ((tid >> 6) & 15) * 16 + (lane & 15);
            int kbase = (tid >> 10) * 32 + (lane >> 4) * 8;
            union { ushort_t u[8]; short8 v; } pk;
            #pragma unroll
            for (int j = 0; j < 8; ++j) {
                int kidx = kbase + j;
                int c = kidx & 255, tap = kidx >> 8;
                pk.u[j] = f2bf(w_def[((size_t)o * C + c) * 9 + tap]);
            }
            *(short8*)(wPack + (size_t)tid * 8) = pk.v;
        } else {
            int t2 = tid - NHS * 16 * 64;             // [0, 9216)
            int lane = t2 & 63;
            int o = ((t2 >> 6) & 1) * 16 + (lane & 15);
            int kbase = (t2 >> 7) * 32 + (lane >> 4) * 8;
            union { ushort_t u[8]; short8 v; } pk;
            #pragma unroll
            for (int j = 0; j < 8; ++j) {
                int kidx = kbase + j;
                int c = kidx & 255, tap = kidx >> 8;
                pk.u[j] = (o < 18) ? f2bf(w_off[((size_t)o * C + c) * 9 + tap]) : (ushort_t)0;
            }
            *(short8*)(wOffA + (size_t)t2 * 8) = pk.v;
        }
    }
}

// ---------------------------------------------------------------------------
// K3: offset conv via MFMA (validated rounds 5-13).  Grid (b,ho) = 256.
// ---------------------------------------------------------------------------
__global__ __launch_bounds__(256) void offconv_all(
    const ushort_t* __restrict__ xt01, const ushort_t* __restrict__ xtD,
    const ushort_t* __restrict__ wOffA, float* __restrict__ offFull)
{
    int orig = blockIdx.x;
    int r = ((orig & 7) << 5) | (orig >> 3);   // XCD swizzle, 256 blocks
    int b = r >> 6, ho = r & 63;
    int tid = threadIdx.x;
    int lane = tid & 63, wv = tid >> 6;
    int px = wv * 16 + (lane & 15);
    int cseg = (lane >> 4) * 8;

    const ushort_t* xtb = (b < 2) ? (xt01 + (size_t)b * HW * C)
                                  : (xtD + (size_t)(b - 2) * HW * C);
    const short8* wA = (const short8*)wOffA;

    f32x4 acc[2];
    acc[0] = (f32x4){0.f, 0.f, 0.f, 0.f};
    acc[1] = (f32x4){0.f, 0.f, 0.f, 0.f};

    #pragma unroll 1
    for (int tap = 0; tap < 9; ++tap) {
        int ky = tap / 3, kx = tap - ky * 3;
        int y  = ho - 1 + ky;
        int xx = px - 1 + kx;
        bool ok = ((unsigned)y < 64u) && ((unsigned)xx < 64u);
        unsigned msk = ok ? 0xffffffffu : 0u;
        int yc = min(max(y, 0), 63), xc = min(max(xx, 0), 63);
        const ushort_t* srcb = xtb + (size_t)(yc * 64 + xc) * C + cseg;

        #pragma unroll
        for (int cs = 0; cs < 8; ++cs) {
            union { u32x4 u; short8 s; } bv;
            bv.u = *(const u32x4*)(srcb + cs * 32);
            bv.u[0] &= msk; bv.u[1] &= msk; bv.u[2] &= msk; bv.u[3] &= msk;
            int ks = tap * 8 + cs;
            short8 aF0 = wA[(size_t)ks * 128 + lane];
            short8 aF1 = wA[(size_t)ks * 128 + 64 + lane];
            acc[0] = __builtin_amdgcn_mfma_f32_16x16x32_bf16(aF0, bv.s, acc[0], 0, 0, 0);
            acc[1] = __builtin_amdgcn_mfma_f32_16x16x32_bf16(aF1, bv.s, acc[1], 0, 0, 0);
        }
    }

    #pragma unroll
    for (int gt = 0; gt < 2; ++gt) {
        #pragma unroll
        for (int j = 0; j < 4; ++j) {
            int oc = gt * 16 + (lane >> 4) * 4 + j;
            if (oc < 18)
                offFull[((size_t)b * 18 + oc) * HW + ho * 64 + px] = acc[gt][j];
        }
    }
}

// ---------------------------------------------------------------------------
// K4: bilinear sample + bf16 MFMA GEMM — the round-12-proven configuration
// (96.45 µs total, no spill): 256o x 32px per block, 512 thr (8 waves, wave
// = 32o x 32px), one pixel per staging thread (rq in [0,32), chunk in [0,16)),
// coalesced 4 x 16B neighbor loads, in-register blend, A single-buffered
// (L2-hot), non-draining barriers, loads one tap in flight.
// Sole addition vs round 12: s_setprio(1/0) around the MFMA loop (T5).
// Grid (bl,ho,pxh) = 256 blocks/launch.  launch_bounds(512,2): VGPR cap 128,
// live state ~100 -> no spill (verified round 12: no scratch traffic).
// ---------------------------------------------------------------------------
__global__ __launch_bounds__(512, 2) void deform_pair(
    const ushort_t* __restrict__ xtB, const float* __restrict__ offFull,
    const ushort_t* __restrict__ wPack, float* __restrict__ out, int pbase)
{
    __shared__ __align__(16) ushort_t sS[2][16][33][8];  // 16.9 KB
    __shared__ float sOff[18][32];                       // 2.3 KB
    __shared__ int   sBase[2][128];                      // run bases (dbuf)
    __shared__ float sWgt[2][32][4];                     // per-px nbr weights

    int orig = blockIdx.x;
    int r = ((orig & 7) << 5) | (orig >> 3);   // XCD swizzle, 256 blocks
    int bl = r >> 7, ho = (r >> 1) & 63, pxh = r & 1;
    int tid = threadIdx.x;
    int lane = tid & 63, wv = tid >> 6;        // 8 waves
    int chunk = tid & 15, rq = (tid >> 4) & 31;  // staging: pixel rq, chunk

    const ushort_t* xtb = xtB + (size_t)bl * HW * C;
    int b = pbase + bl;

    // this row's offsets for our px half
    for (int idx = tid; idx < 18 * 32; idx += 512) {
        int oc = idx >> 5, p2 = idx & 31;
        sOff[oc][p2] = offFull[((size_t)b * 18 + oc) * HW + ho * 64 + pxh * 32 + p2];
    }
    __syncthreads();

    f32x4 acc2[2][2];
    #pragma unroll
    for (int i = 0; i < 2; ++i)
        #pragma unroll
        for (int j = 0; j < 2; ++j) acc2[i][j] = (f32x4){0.f, 0.f, 0.f, 0.f};

    // run bases + per-pixel neighbor weights (validity folded in), dbuf by tap
    auto computeBase = [&](int tap, int buf) {
        if (tid < 128) {
            int n = tid >> 5, q = tid & 31;
            int ky = tap / 3, kx = tap - ky * 3;
            float offy = sOff[2 * tap][q];
            float offx = sOff[2 * tap + 1][q];
            float py  = offy + (float)(ho - 1 + ky);
            float pxf = offx + (float)(pxh * 32 + q - 1 + kx);
            float y0f = floorf(py), x0f = floorf(pxf);
            float wy1 = py - y0f, wx1 = pxf - x0f;
            int y0 = (int)y0f, x0 = (int)x0f;
            int dy = n >> 1, dx = n & 1;
            int yy = y0 + dy, xx = x0 + dx;
            float wn = (dy ? wy1 : (1.f - wy1)) * (dx ? wx1 : (1.f - wx1));
            wn *= (((unsigned)yy < 64u) ? 1.f : 0.f) * (((unsigned)xx < 64u) ? 1.f : 0.f);
            int yc = min(max(yy, 0), 63), xc = min(max(xx, 0), 63);
            sBase[buf][tid] = (yc * 64 + xc) * C;
            sWgt[buf][q][n] = wn;
        }
    };

    auto loadBases = [&](int buf, int* rb) {
        #pragma unroll
        for (int n = 0; n < 4; ++n) rb[n] = sBase[buf][n * 32 + rq];
    };

    // coalesced: 4 x 16B, neighbor n of pixel rq, channels sub*128 + chunk*8
    auto issueC = [&](const int* rb, int sub, u32x4* L) {
        #pragma unroll
        for (int n = 0; n < 4; ++n)
            L[n] = *(const u32x4*)(xtb + rb[n] + sub * 128 + chunk * 8);
    };

    // in-register blend: one pixel (rq), 4 neighbors -> sS[p][chunk][rq]
    auto blendDirect = [&](const u32x4* L, const float* w, int p) {
        unsigned pk[4];
        #pragma unroll
        for (int j = 0; j < 4; ++j) {
            float f0l = __uint_as_float(L[0][j] << 16);
            float f0h = __uint_as_float(L[0][j] & 0xffff0000u);
            float f1l = __uint_as_float(L[1][j] << 16);
            float f1h = __uint_as_float(L[1][j] & 0xffff0000u);
            float f2l = __uint_as_float(L[2][j] << 16);
            float f2h = __uint_as_float(L[2][j] & 0xffff0000u);
            float f3l = __uint_as_float(L[3][j] << 16);
            float f3h = __uint_as_float(L[3][j] & 0xffff0000u);
            float lo = fmaf(w[0], f0l, fmaf(w[1], f1l, fmaf(w[2], f2l, w[3] * f3l)));
            float hi = fmaf(w[0], f0h, fmaf(w[1], f1h, fmaf(w[2], f2h, w[3] * f3h)));
            asm("v_cvt_pk_bf16_f32 %0, %1, %2" : "=v"(pk[j]) : "v"(lo), "v"(hi));
        }
        u32x4 wvec = (u32x4){pk[0], pk[1], pk[2], pk[3]};
        *(u32x4*)&sS[p][chunk][rq][0] = wvec;
    };

    int gt0 = wv * 2;
    const short8* wpB = (const short8*)wPack;

    auto mfmaPhaseA = [&](int ks4base, int p) {   // load A (single-buf) + MFMA
        __builtin_amdgcn_s_setprio(1);            // T5: favor MFMA wave
        #pragma unroll
        for (int h = 0; h < 4; ++h) {
            size_t an = ((size_t)(ks4base + h) * 16 + gt0) * 64 + lane;
            short8 a0 = wpB[an];
            short8 a1 = wpB[an + 64];
            #pragma unroll
            for (int pt = 0; pt < 2; ++pt) {
                short8 bF = *(const short8*)&sS[p][h * 4 + (lane >> 4)][pt * 16 + (lane & 15)][0];
                acc2[0][pt] = __builtin_amdgcn_mfma_f32_16x16x32_bf16(a0, bF, acc2[0][pt], 0, 0, 0);
                acc2[1][pt] = __builtin_amdgcn_mfma_f32_16x16x32_bf16(a1, bF, acc2[1][pt], 0, 0, 0);
            }
        }
        __builtin_amdgcn_s_setprio(0);
    };

    u32x4 LA[4], LB[4];

    // prologue
    computeBase(0, 0);
    block_sync_lds();
    {
        int rb0[4];
        loadBases(0, rb0);
        issueC(rb0, 0, LA);
        issueC(rb0, 1, LB);
    }

    int p = 0;
    #pragma unroll 1
    for (int tap = 0; tap < 9; ++tap) {
        float wcur[4];
        *(float4*)&wcur[0] = *(const float4*)&sWgt[tap & 1][rq][0];
        if (tap < 8) computeBase(tap + 1, (tap + 1) & 1);

        int rb[4];
        // ---- sub 0 ----
        blendDirect(LA, wcur, p);
        block_sync_lds();                               // sS[p] + next bases visible
        if (tap < 8) { loadBases((tap + 1) & 1, rb); issueC(rb, 0, LA); }
        mfmaPhaseA(tap * 8, p);
        p ^= 1;
        // ---- sub 1 ----
        blendDirect(LB, wcur, p);
        block_sync_lds();
        if (tap < 8) issueC(rb, 1, LB);
        mfmaPhaseA(tap * 8 + 4, p);
        p ^= 1;
    }

    // epilogue: D[row=(l>>4)*4+j][col=l&15]
    #pragma unroll
    for (int ot = 0; ot < 2; ++ot) {
        int o = wv * 32 + ot * 16 + (lane >> 4) * 4;
        #pragma unroll
        for (int pt = 0; pt < 2; ++pt) {
            int pxx = pxh * 32 + pt * 16 + (lane & 15);
            #pragma unroll
            for (int j = 0; j < 4; ++j)
                out[(((size_t)b * OCH + (o + j)) * H + ho) * W + pxx] = acc2[ot][pt][j];
        }
    }
}

// ---------------------------------------------------------------------------
extern "C" void kernel_launch(void* const* d_in, const int* in_sizes, int n_in,
                              void* d_out, int out_size, void* d_ws, size_t ws_size,
                              hipStream_t stream)
{
    const float* x     = (const float*)d_in[0];
    const float* w_off = (const float*)d_in[1];
    const float* w_def = (const float*)d_in[2];
    float* out = (float*)d_out;

    // ws: xt01[4.19MB] | wPack[1.18MB] | wOffA[147KB] | offFull[1.18MB]
    // total 6,701,056 B (proven).  xt23 lives in d_out's batch-0 region:
    // written by prep, read by offconv + deform(pbase=2) (writes out[b2,b3]
    // only), then overwritten by deform(pbase=0)'s out[b0] stores.
    ushort_t* xt01    = (ushort_t*)d_ws;
    ushort_t* wPack   = xt01 + (size_t)2 * HW * C;
    ushort_t* wOffA   = wPack + (size_t)NHS * 16 * 64 * 8;
    float*    offFull = (float*)(wOffA + (size_t)NHS * 2 * 64 * 8);
    ushort_t* xtD     = (ushort_t*)d_out;   // batch 2,3 xt scratch

    prep_all<<<1348, 256, 0, stream>>>(x, w_def, w_off, xt01, xtD, wPack, wOffA);
    offconv_all<<<256, 256, 0, stream>>>(xt01, xtD, wOffA, offFull);
    deform_pair<<<256, 512, 0, stream>>>(xtD, offFull, wPack, out, 2);
    deform_pair<<<256, 512, 0, stream>>>(xt01, offFull, wPack, out, 0);
}

// Round 18
// 84.751 us; speedup vs baseline: 1.6496x; 1.1146x over previous
//
#include <hip/hip_runtime.h>

typedef __attribute__((ext_vector_type(8))) short short8;
typedef __attribute__((ext_vector_type(4))) float f32x4;
typedef __attribute__((ext_vector_type(4))) unsigned int u32x4;
typedef unsigned short ushort_t;

constexpr int B   = 4;
constexpr int C   = 256;
constexpr int H   = 64;
constexpr int W   = 64;
constexpr int HW  = H * W;          // 4096
constexpr int OCH = 256;
constexpr int KT  = 9 * C;          // 2304, k order: k = tap*256 + c
constexpr int NHS = KT / 32;        // 72 half-steps (MFMA K=32)

__device__ __forceinline__ ushort_t f2bf(float f) {
    unsigned u = __float_as_uint(f);
    u += 0x7FFF + ((u >> 16) & 1);      // RNE
    return (ushort_t)(u >> 16);
}

// Barrier that does NOT drain vmcnt: LDS writes are made visible
// (lgkmcnt(0)), but in-register global loads stay in flight across it.
__device__ __forceinline__ void block_sync_lds() {
    asm volatile("s_waitcnt lgkmcnt(0)" ::: "memory");
    __builtin_amdgcn_s_barrier();
    asm volatile("" ::: "memory");
}

// ---------------------------------------------------------------------------
// K0: prep = transpose (blocks 0..1023) + weight packing (blocks 1024..1347).
// Transpose: xt[b][y][x][c] (bf16) <- x[b][c][y][x] (f32); b<2 -> xt01 (ws),
// b>=2 -> xtD (d_out batch-0 scratch).  Pack: validated rounds 2-17.
// ---------------------------------------------------------------------------
__global__ __launch_bounds__(256) void prep_all(
    const float* __restrict__ x, const float* __restrict__ w_def,
    const float* __restrict__ w_off, ushort_t* __restrict__ xt01,
    ushort_t* __restrict__ xtD, ushort_t* __restrict__ wPack,
    ushort_t* __restrict__ wOffA)
{
    __shared__ float sT[64][65];
    int blk = blockIdx.x;
    if (blk < 1024) {
        int cg  = blk & 3;               // channel group of 64
        int y   = (blk >> 2) & 63;
        int b   = blk >> 8;              // 0..3
        int t   = threadIdx.x;
        int col = t & 63, r4 = t >> 6;

        const float* xp = x + (((size_t)b * C + cg * 64) * H + y) * W;
        #pragma unroll
        for (int i = 0; i < 16; ++i) {
            int cl = i * 4 + r4;
            sT[cl][col] = xp[(size_t)cl * HW + col];
        }
        __syncthreads();
        ushort_t* base = (b < 2) ? (xt01 + (size_t)b * HW * C)
                                 : (xtD + (size_t)(b - 2) * HW * C);
        ushort_t* op = base + ((size_t)y * W) * C + cg * 64;
        #pragma unroll
        for (int i = 0; i < 16; ++i) {
            int xl = i * 4 + r4;
            op[(size_t)xl * C + col] = f2bf(sT[col][xl]);
        }
    } else {
        int tid = (blk - 1024) * 256 + threadIdx.x;   // [0, 82944)
        if (tid < NHS * 16 * 64) {
            int lane = tid & 63;
            int o = ((tid >> 6) & 15) * 16 + (lane & 15);
            int kbase = (tid >> 10) * 32 + (lane >> 4) * 8;
            union { ushort_t u[8]; short8 v; } pk;
            #pragma unroll
            for (int j = 0; j < 8; ++j) {
                int kidx = kbase + j;
                int c = kidx & 255, tap = kidx >> 8;
                pk.u[j] = f2bf(w_def[((size_t)o * C + c) * 9 + tap]);
            }
            *(short8*)(wPack + (size_t)tid * 8) = pk.v;
        } else {
            int t2 = tid - NHS * 16 * 64;             // [0, 9216)
            int lane = t2 & 63;
            int o = ((t2 >> 6) & 1) * 16 + (lane & 15);
            int kbase = (t2 >> 7) * 32 + (lane >> 4) * 8;
            union { ushort_t u[8]; short8 v; } pk;
            #pragma unroll
            for (int j = 0; j < 8; ++j) {
                int kidx = kbase + j;
                int c = kidx & 255, tap = kidx >> 8;
                pk.u[j] = (o < 18) ? f2bf(w_off[((size_t)o * C + c) * 9 + tap]) : (ushort_t)0;
            }
            *(short8*)(wOffA + (size_t)t2 * 8) = pk.v;
        }
    }
}

// ---------------------------------------------------------------------------
// K4: FUSED {offset-conv prologue + bilinear sample + bf16 MFMA GEMM}.
// r17-proven main loop (94.46 µs config: 256o x 32px, 512 thr, coalesced
// loads + in-register blend, non-draining barriers, setprio around MFMA,
// launch_bounds(512,2) -> VGPR cap 128, no spill).
// NEW: offset conv computed in-block via split-K MFMA prologue — wave wv
// handles K-steps [wv*9, wv*9+9), partials reduced through LDS into sOff.
// Offsets never touch global memory; the offconv_all launch is deleted.
// Grid (bl,ho,pxh) = 256 blocks/launch.
// ---------------------------------------------------------------------------
__global__ __launch_bounds__(512, 2) void deform_pair(
    const ushort_t* __restrict__ xtB, const ushort_t* __restrict__ wOffA,
    const ushort_t* __restrict__ wPack, float* __restrict__ out, int pbase)
{
    __shared__ __align__(16) ushort_t sS[2][16][33][8];  // 16.9 KB
    __shared__ float sOff[18][32];                       // 2.3 KB
    __shared__ float sPart[8][18][32];                   // 18.4 KB (prologue)
    __shared__ int   sBase[2][128];                      // run bases (dbuf)
    __shared__ float sWgt[2][32][4];                     // per-px nbr weights

    int orig = blockIdx.x;
    int r = ((orig & 7) << 5) | (orig >> 3);   // XCD swizzle, 256 blocks
    int bl = r >> 7, ho = (r >> 1) & 63, pxh = r & 1;
    int tid = threadIdx.x;
    int lane = tid & 63, wv = tid >> 6;        // 8 waves
    int chunk = tid & 15, rq = (tid >> 4) & 31;  // staging: pixel rq, chunk

    const ushort_t* xtb = xtB + (size_t)bl * HW * C;
    int b = pbase + bl;

    // ---------------- offset-conv prologue (split-K MFMA) ----------------
    {
        const short8* wA = (const short8*)wOffA;
        f32x4 pacc[2][2];
        #pragma unroll
        for (int i = 0; i < 2; ++i)
            #pragma unroll
            for (int j = 0; j < 2; ++j) pacc[i][j] = (f32x4){0.f, 0.f, 0.f, 0.f};

        #pragma unroll 1
        for (int i = 0; i < 9; ++i) {
            int ks = wv * 9 + i;               // this wave's K-step
            int tap = ks >> 3, cs = ks & 7;
            int ky = tap / 3, kx = tap - ky * 3;
            int y  = ho - 1 + ky;
            int yc = min(max(y, 0), 63);
            bool yok = ((unsigned)y < 64u);
            short8 a0 = wA[(size_t)ks * 128 + lane];
            short8 a1 = wA[(size_t)ks * 128 + 64 + lane];
            #pragma unroll
            for (int pt = 0; pt < 2; ++pt) {
                int px = pxh * 32 + pt * 16 + (lane & 15);
                int xx = px - 1 + kx;
                bool ok = yok && ((unsigned)xx < 64u);
                unsigned msk = ok ? 0xffffffffu : 0u;
                int xc = min(max(xx, 0), 63);
                const ushort_t* srcb = xtb + (size_t)(yc * 64 + xc) * C
                                       + cs * 32 + (lane >> 4) * 8;
                union { u32x4 u; short8 s; } bv;
                bv.u = *(const u32x4*)srcb;
                bv.u[0] &= msk; bv.u[1] &= msk; bv.u[2] &= msk; bv.u[3] &= msk;
                pacc[0][pt] = __builtin_amdgcn_mfma_f32_16x16x32_bf16(a0, bv.s, pacc[0][pt], 0, 0, 0);
                pacc[1][pt] = __builtin_amdgcn_mfma_f32_16x16x32_bf16(a1, bv.s, pacc[1][pt], 0, 0, 0);
            }
        }
        // write partials (D: row=(l>>4)*4+j, col=l&15), only oc<18
        #pragma unroll
        for (int gt = 0; gt < 2; ++gt) {
            #pragma unroll
            for (int pt = 0; pt < 2; ++pt) {
                #pragma unroll
                for (int j = 0; j < 4; ++j) {
                    int oc = gt * 16 + (lane >> 4) * 4 + j;
                    if (oc < 18)
                        sPart[wv][oc][pt * 16 + (lane & 15)] = pacc[gt][pt][j];
                }
            }
        }
    }
    __syncthreads();
    for (int idx = tid; idx < 18 * 32; idx += 512) {
        int oc = idx >> 5, q = idx & 31;
        float s = 0.f;
        #pragma unroll
        for (int g = 0; g < 8; ++g) s += sPart[g][oc][q];
        sOff[oc][q] = s;
    }
    __syncthreads();

    // ---------------- main loop (r17-identical) ----------------
    f32x4 acc2[2][2];
    #pragma unroll
    for (int i = 0; i < 2; ++i)
        #pragma unroll
        for (int j = 0; j < 2; ++j) acc2[i][j] = (f32x4){0.f, 0.f, 0.f, 0.f};

    // run bases + per-pixel neighbor weights (validity folded in), dbuf by tap
    auto computeBase = [&](int tap, int buf) {
        if (tid < 128) {
            int n = tid >> 5, q = tid & 31;
            int ky = tap / 3, kx = tap - ky * 3;
            float offy = sOff[2 * tap][q];
            float offx = sOff[2 * tap + 1][q];
            float py  = offy + (float)(ho - 1 + ky);
            float pxf = offx + (float)(pxh * 32 + q - 1 + kx);
            float y0f = floorf(py), x0f = floorf(pxf);
            float wy1 = py - y0f, wx1 = pxf - x0f;
            int y0 = (int)y0f, x0 = (int)x0f;
            int dy = n >> 1, dx = n & 1;
            int yy = y0 + dy, xx = x0 + dx;
            float wn = (dy ? wy1 : (1.f - wy1)) * (dx ? wx1 : (1.f - wx1));
            wn *= (((unsigned)yy < 64u) ? 1.f : 0.f) * (((unsigned)xx < 64u) ? 1.f : 0.f);
            int yc = min(max(yy, 0), 63), xc = min(max(xx, 0), 63);
            sBase[buf][tid] = (yc * 64 + xc) * C;
            sWgt[buf][q][n] = wn;
        }
    };

    auto loadBases = [&](int buf, int* rb) {
        #pragma unroll
        for (int n = 0; n < 4; ++n) rb[n] = sBase[buf][n * 32 + rq];
    };

    // coalesced: 4 x 16B, neighbor n of pixel rq, channels sub*128 + chunk*8
    auto issueC = [&](const int* rb, int sub, u32x4* L) {
        #pragma unroll
        for (int n = 0; n < 4; ++n)
            L[n] = *(const u32x4*)(xtb + rb[n] + sub * 128 + chunk * 8);
    };

    // in-register blend: one pixel (rq), 4 neighbors -> sS[p][chunk][rq]
    auto blendDirect = [&](const u32x4* L, const float* w, int p) {
        unsigned pk[4];
        #pragma unroll
        for (int j = 0; j < 4; ++j) {
            float f0l = __uint_as_float(L[0][j] << 16);
            float f0h = __uint_as_float(L[0][j] & 0xffff0000u);
            float f1l = __uint_as_float(L[1][j] << 16);
            float f1h = __uint_as_float(L[1][j] & 0xffff0000u);
            float f2l = __uint_as_float(L[2][j] << 16);
            float f2h = __uint_as_float(L[2][j] & 0xffff0000u);
            float f3l = __uint_as_float(L[3][j] << 16);
            float f3h = __uint_as_float(L[3][j] & 0xffff0000u);
            float lo = fmaf(w[0], f0l, fmaf(w[1], f1l, fmaf(w[2], f2l, w[3] * f3l)));
            float hi = fmaf(w[0], f0h, fmaf(w[1], f1h, fmaf(w[2], f2h, w[3] * f3h)));
            asm("v_cvt_pk_bf16_f32 %0, %1, %2" : "=v"(pk[j]) : "v"(lo), "v"(hi));
        }
        u32x4 wvec = (u32x4){pk[0], pk[1], pk[2], pk[3]};
        *(u32x4*)&sS[p][chunk][rq][0] = wvec;
    };

    int gt0 = wv * 2;
    const short8* wpB = (const short8*)wPack;

    auto mfmaPhaseA = [&](int ks4base, int p) {   // load A (single-buf) + MFMA
        __builtin_amdgcn_s_setprio(1);            // T5: favor MFMA wave
        #pragma unroll
        for (int h = 0; h < 4; ++h) {
            size_t an = ((size_t)(ks4base + h) * 16 + gt0) * 64 + lane;
            short8 a0 = wpB[an];
            short8 a1 = wpB[an + 64];
            #pragma unroll
            for (int pt = 0; pt < 2; ++pt) {
                short8 bF = *(const short8*)&sS[p][h * 4 + (lane >> 4)][pt * 16 + (lane & 15)][0];
                acc2[0][pt] = __builtin_amdgcn_mfma_f32_16x16x32_bf16(a0, bF, acc2[0][pt], 0, 0, 0);
                acc2[1][pt] = __builtin_amdgcn_mfma_f32_16x16x32_bf16(a1, bF, acc2[1][pt], 0, 0, 0);
            }
        }
        __builtin_amdgcn_s_setprio(0);
    };

    u32x4 LA[4], LB[4];

    // prologue of main pipeline
    computeBase(0, 0);
    block_sync_lds();
    {
        int rb0[4];
        loadBases(0, rb0);
        issueC(rb0, 0, LA);
        issueC(rb0, 1, LB);
    }

    int p = 0;
    #pragma unroll 1
    for (int tap = 0; tap < 9; ++tap) {
        float wcur[4];
        *(float4*)&wcur[0] = *(const float4*)&sWgt[tap & 1][rq][0];
        if (tap < 8) computeBase(tap + 1, (tap + 1) & 1);

        int rb[4];
        // ---- sub 0 ----
        blendDirect(LA, wcur, p);
        block_sync_lds();                               // sS[p] + next bases visible
        if (tap < 8) { loadBases((tap + 1) & 1, rb); issueC(rb, 0, LA); }
        mfmaPhaseA(tap * 8, p);
        p ^= 1;
        // ---- sub 1 ----
        blendDirect(LB, wcur, p);
        block_sync_lds();
        if (tap < 8) issueC(rb, 1, LB);
        mfmaPhaseA(tap * 8 + 4, p);
        p ^= 1;
    }

    // epilogue: D[row=(l>>4)*4+j][col=l&15]
    #pragma unroll
    for (int ot = 0; ot < 2; ++ot) {
        int o = wv * 32 + ot * 16 + (lane >> 4) * 4;
        #pragma unroll
        for (int pt = 0; pt < 2; ++pt) {
            int pxx = pxh * 32 + pt * 16 + (lane & 15);
            #pragma unroll
            for (int j = 0; j < 4; ++j)
                out[(((size_t)b * OCH + (o + j)) * H + ho) * W + pxx] = acc2[ot][pt][j];
        }
    }
}

// ---------------------------------------------------------------------------
extern "C" void kernel_launch(void* const* d_in, const int* in_sizes, int n_in,
                              void* d_out, int out_size, void* d_ws, size_t ws_size,
                              hipStream_t stream)
{
    const float* x     = (const float*)d_in[0];
    const float* w_off = (const float*)d_in[1];
    const float* w_def = (const float*)d_in[2];
    float* out = (float*)d_out;

    // ws: xt01[4.19MB] | wPack[1.18MB] | wOffA[147KB] = 5.52 MB (< proven 6.7).
    // xt23 lives in d_out's batch-0 region: written by prep, read by
    // deform(pbase=2) (writes out[b2,b3] only), then overwritten by
    // deform(pbase=0)'s out[b0] stores.
    ushort_t* xt01  = (ushort_t*)d_ws;
    ushort_t* wPack = xt01 + (size_t)2 * HW * C;
    ushort_t* wOffA = wPack + (size_t)NHS * 16 * 64 * 8;
    ushort_t* xtD   = (ushort_t*)d_out;   // batch 2,3 xt scratch

    prep_all<<<1348, 256, 0, stream>>>(x, w_def, w_off, xt01, xtD, wPack, wOffA);
    deform_pair<<<256, 512, 0, stream>>>(xtD, wOffA, wPack, out, 2);
    deform_pair<<<256, 512, 0, stream>>>(xt01, wOffA, wPack, out, 0);
}

// Round 19
// 66.458 us; speedup vs baseline: 2.1037x; 1.2753x over previous
//
#include <hip/hip_runtime.h>

typedef __attribute__((ext_vector_type(8))) short short8;
typedef __attribute__((ext_vector_type(4))) float f32x4;
typedef __attribute__((ext_vector_type(4))) unsigned int u32x4;
typedef unsigned short ushort_t;

constexpr int B   = 4;
constexpr int C   = 256;
constexpr int H   = 64;
constexpr int W   = 64;
constexpr int HW  = H * W;          // 4096
constexpr int OCH = 256;
constexpr int KT  = 9 * C;          // 2304, k order: k = tap*256 + c
constexpr int NHS = KT / 32;        // 72 half-steps (MFMA K=32)

__device__ __forceinline__ ushort_t f2bf(float f) {
    unsigned u = __float_as_uint(f);
    u += 0x7FFF + ((u >> 16) & 1);      // RNE
    return (ushort_t)(u >> 16);
}

// Barrier that does NOT drain vmcnt: LDS writes are made visible
// (lgkmcnt(0)), but in-register global loads stay in flight across it.
__device__ __forceinline__ void block_sync_lds() {
    asm volatile("s_waitcnt lgkmcnt(0)" ::: "memory");
    __builtin_amdgcn_s_barrier();
    asm volatile("" ::: "memory");
}

// ---------------------------------------------------------------------------
// K0: prep = transpose (blocks 0..1023) + weight packing (blocks 1024..1347).
// Transpose: xt[b][y][x][c] (bf16) <- x[b][c][y][x] (f32); b<2 -> xt01 (ws),
// b>=2 -> xtD (d_out batch-0 scratch).  Pack: validated rounds 2-18.
// ---------------------------------------------------------------------------
__global__ __launch_bounds__(256) void prep_all(
    const float* __restrict__ x, const float* __restrict__ w_def,
    const float* __restrict__ w_off, ushort_t* __restrict__ xt01,
    ushort_t* __restrict__ xtD, ushort_t* __restrict__ wPack,
    ushort_t* __restrict__ wOffA)
{
    __shared__ float sT[64][65];
    int blk = blockIdx.x;
    if (blk < 1024) {
        int cg  = blk & 3;               // channel group of 64
        int y   = (blk >> 2) & 63;
        int b   = blk >> 8;              // 0..3
        int t   = threadIdx.x;
        int col = t & 63, r4 = t >> 6;

        const float* xp = x + (((size_t)b * C + cg * 64) * H + y) * W;
        #pragma unroll
        for (int i = 0; i < 16; ++i) {
            int cl = i * 4 + r4;
            sT[cl][col] = xp[(size_t)cl * HW + col];
        }
        __syncthreads();
        ushort_t* base = (b < 2) ? (xt01 + (size_t)b * HW * C)
                                 : (xtD + (size_t)(b - 2) * HW * C);
        ushort_t* op = base + ((size_t)y * W) * C + cg * 64;
        #pragma unroll
        for (int i = 0; i < 16; ++i) {
            int xl = i * 4 + r4;
            op[(size_t)xl * C + col] = f2bf(sT[col][xl]);
        }
    } else {
        int tid = (blk - 1024) * 256 + threadIdx.x;   // [0, 82944)
        if (tid < NHS * 16 * 64) {
            int lane = tid & 63;
            int o = ((tid >> 6) & 15) * 16 + (lane & 15);
            int kbase = (tid >> 10) * 32 + (lane >> 4) * 8;
            union { ushort_t u[8]; short8 v; } pk;
            #pragma unroll
            for (int j = 0; j < 8; ++j) {
                int kidx = kbase + j;
                int c = kidx & 255, tap = kidx >> 8;
                pk.u[j] = f2bf(w_def[((size_t)o * C + c) * 9 + tap]);
            }
            *(short8*)(wPack + (size_t)tid * 8) = pk.v;
        } else {
            int t2 = tid - NHS * 16 * 64;             // [0, 9216)
            int lane = t2 & 63;
            int o = ((t2 >> 6) & 1) * 16 + (lane & 15);
            int kbase = (t2 >> 7) * 32 + (lane >> 4) * 8;
            union { ushort_t u[8]; short8 v; } pk;
            #pragma unroll
            for (int j = 0; j < 8; ++j) {
                int kidx = kbase + j;
                int c = kidx & 255, tap = kidx >> 8;
                pk.u[j] = (o < 18) ? f2bf(w_off[((size_t)o * C + c) * 9 + tap]) : (ushort_t)0;
            }
            *(short8*)(wOffA + (size_t)t2 * 8) = pk.v;
        }
    }
}

// ---------------------------------------------------------------------------
// K4: FUSED {offset-conv MFMA prologue + bilinear sample + bf16 MFMA GEMM}.
// r18 structure (84.75 µs config) with ONE change: A-fragments for each sub
// are batch-loaded into a static short8 A[8] array ISSUED BEFORE the blend +
// barrier (global loads stay in flight across the non-draining barrier), so
// the MFMA phase pays one L2 latency per phase instead of eight.  r18's
// VGPR_Count=48 showed the compiler had serialized per-h A loads.
// Grid (bl,ho,pxh) = 256 blocks/launch, 512 thr, launch_bounds(512,2).
// ---------------------------------------------------------------------------
__global__ __launch_bounds__(512, 2) void deform_pair(
    const ushort_t* __restrict__ xtB, const ushort_t* __restrict__ wOffA,
    const ushort_t* __restrict__ wPack, float* __restrict__ out, int pbase)
{
    __shared__ __align__(16) ushort_t sS[2][16][33][8];  // 16.9 KB
    __shared__ float sOff[18][32];                       // 2.3 KB
    __shared__ float sPart[8][18][32];                   // 18.4 KB (prologue)
    __shared__ int   sBase[2][128];                      // run bases (dbuf)
    __shared__ float sWgt[2][32][4];                     // per-px nbr weights

    int orig = blockIdx.x;
    int r = ((orig & 7) << 5) | (orig >> 3);   // XCD swizzle, 256 blocks
    int bl = r >> 7, ho = (r >> 1) & 63, pxh = r & 1;
    int tid = threadIdx.x;
    int lane = tid & 63, wv = tid >> 6;        // 8 waves
    int chunk = tid & 15, rq = (tid >> 4) & 31;  // staging: pixel rq, chunk

    const ushort_t* xtb = xtB + (size_t)bl * HW * C;
    int b = pbase + bl;

    // ---------------- offset-conv prologue (split-K MFMA) ----------------
    {
        const short8* wA = (const short8*)wOffA;
        f32x4 pacc[2][2];
        #pragma unroll
        for (int i = 0; i < 2; ++i)
            #pragma unroll
            for (int j = 0; j < 2; ++j) pacc[i][j] = (f32x4){0.f, 0.f, 0.f, 0.f};

        #pragma unroll 1
        for (int i = 0; i < 9; ++i) {
            int ks = wv * 9 + i;               // this wave's K-step
            int tap = ks >> 3, cs = ks & 7;
            int ky = tap / 3, kx = tap - ky * 3;
            int y  = ho - 1 + ky;
            int yc = min(max(y, 0), 63);
            bool yok = ((unsigned)y < 64u);
            short8 a0 = wA[(size_t)ks * 128 + lane];
            short8 a1 = wA[(size_t)ks * 128 + 64 + lane];
            #pragma unroll
            for (int pt = 0; pt < 2; ++pt) {
                int px = pxh * 32 + pt * 16 + (lane & 15);
                int xx = px - 1 + kx;
                bool ok = yok && ((unsigned)xx < 64u);
                unsigned msk = ok ? 0xffffffffu : 0u;
                int xc = min(max(xx, 0), 63);
                const ushort_t* srcb = xtb + (size_t)(yc * 64 + xc) * C
                                       + cs * 32 + (lane >> 4) * 8;
                union { u32x4 u; short8 s; } bv;
                bv.u = *(const u32x4*)srcb;
                bv.u[0] &= msk; bv.u[1] &= msk; bv.u[2] &= msk; bv.u[3] &= msk;
                pacc[0][pt] = __builtin_amdgcn_mfma_f32_16x16x32_bf16(a0, bv.s, pacc[0][pt], 0, 0, 0);
                pacc[1][pt] = __builtin_amdgcn_mfma_f32_16x16x32_bf16(a1, bv.s, pacc[1][pt], 0, 0, 0);
            }
        }
        // write partials (D: row=(l>>4)*4+j, col=l&15), only oc<18
        #pragma unroll
        for (int gt = 0; gt < 2; ++gt) {
            #pragma unroll
            for (int pt = 0; pt < 2; ++pt) {
                #pragma unroll
                for (int j = 0; j < 4; ++j) {
                    int oc = gt * 16 + (lane >> 4) * 4 + j;
                    if (oc < 18)
                        sPart[wv][oc][pt * 16 + (lane & 15)] = pacc[gt][pt][j];
                }
            }
        }
    }
    __syncthreads();
    for (int idx = tid; idx < 18 * 32; idx += 512) {
        int oc = idx >> 5, q = idx & 31;
        float s = 0.f;
        #pragma unroll
        for (int g = 0; g < 8; ++g) s += sPart[g][oc][q];
        sOff[oc][q] = s;
    }
    __syncthreads();

    // ---------------- main loop ----------------
    f32x4 acc2[2][2];
    #pragma unroll
    for (int i = 0; i < 2; ++i)
        #pragma unroll
        for (int j = 0; j < 2; ++j) acc2[i][j] = (f32x4){0.f, 0.f, 0.f, 0.f};

    // run bases + per-pixel neighbor weights (validity folded in), dbuf by tap
    auto computeBase = [&](int tap, int buf) {
        if (tid < 128) {
            int n = tid >> 5, q = tid & 31;
            int ky = tap / 3, kx = tap - ky * 3;
            float offy = sOff[2 * tap][q];
            float offx = sOff[2 * tap + 1][q];
            float py  = offy + (float)(ho - 1 + ky);
            float pxf = offx + (float)(pxh * 32 + q - 1 + kx);
            float y0f = floorf(py), x0f = floorf(pxf);
            float wy1 = py - y0f, wx1 = pxf - x0f;
            int y0 = (int)y0f, x0 = (int)x0f;
            int dy = n >> 1, dx = n & 1;
            int yy = y0 + dy, xx = x0 + dx;
            float wn = (dy ? wy1 : (1.f - wy1)) * (dx ? wx1 : (1.f - wx1));
            wn *= (((unsigned)yy < 64u) ? 1.f : 0.f) * (((unsigned)xx < 64u) ? 1.f : 0.f);
            int yc = min(max(yy, 0), 63), xc = min(max(xx, 0), 63);
            sBase[buf][tid] = (yc * 64 + xc) * C;
            sWgt[buf][q][n] = wn;
        }
    };

    auto loadBases = [&](int buf, int* rb) {
        #pragma unroll
        for (int n = 0; n < 4; ++n) rb[n] = sBase[buf][n * 32 + rq];
    };

    // coalesced: 4 x 16B, neighbor n of pixel rq, channels sub*128 + chunk*8
    auto issueC = [&](const int* rb, int sub, u32x4* L) {
        #pragma unroll
        for (int n = 0; n < 4; ++n)
            L[n] = *(const u32x4*)(xtb + rb[n] + sub * 128 + chunk * 8);
    };

    // in-register blend: one pixel (rq), 4 neighbors -> sS[p][chunk][rq]
    auto blendDirect = [&](const u32x4* L, const float* w, int p) {
        unsigned pk[4];
        #pragma unroll
        for (int j = 0; j < 4; ++j) {
            float f0l = __uint_as_float(L[0][j] << 16);
            float f0h = __uint_as_float(L[0][j] & 0xffff0000u);
            float f1l = __uint_as_float(L[1][j] << 16);
            float f1h = __uint_as_float(L[1][j] & 0xffff0000u);
            float f2l = __uint_as_float(L[2][j] << 16);
            float f2h = __uint_as_float(L[2][j] & 0xffff0000u);
            float f3l = __uint_as_float(L[3][j] << 16);
            float f3h = __uint_as_float(L[3][j] & 0xffff0000u);
            float lo = fmaf(w[0], f0l, fmaf(w[1], f1l, fmaf(w[2], f2l, w[3] * f3l)));
            float hi = fmaf(w[0], f0h, fmaf(w[1], f1h, fmaf(w[2], f2h, w[3] * f3h)));
            asm("v_cvt_pk_bf16_f32 %0, %1, %2" : "=v"(pk[j]) : "v"(lo), "v"(hi));
        }
        u32x4 wvec = (u32x4){pk[0], pk[1], pk[2], pk[3]};
        *(u32x4*)&sS[p][chunk][rq][0] = wvec;
    };

    int gt0 = wv * 2;
    const short8* wpB = (const short8*)wPack;

    // batch-issue the 8 A-fragments of one sub (loads pipeline together;
    // issued BEFORE blend+barrier so latency hides under them)
    auto loadA8 = [&](int ks4base, short8* A) {
        #pragma unroll
        for (int h = 0; h < 4; ++h) {
            size_t an = ((size_t)(ks4base + h) * 16 + gt0) * 64 + lane;
            A[2 * h]     = wpB[an];
            A[2 * h + 1] = wpB[an + 64];
        }
    };

    auto mfmaPhase = [&](const short8* A, int p) {
        __builtin_amdgcn_s_setprio(1);            // T5: favor MFMA wave
        #pragma unroll
        for (int h = 0; h < 4; ++h) {
            #pragma unroll
            for (int pt = 0; pt < 2; ++pt) {
                short8 bF = *(const short8*)&sS[p][h * 4 + (lane >> 4)][pt * 16 + (lane & 15)][0];
                acc2[0][pt] = __builtin_amdgcn_mfma_f32_16x16x32_bf16(A[2 * h],     bF, acc2[0][pt], 0, 0, 0);
                acc2[1][pt] = __builtin_amdgcn_mfma_f32_16x16x32_bf16(A[2 * h + 1], bF, acc2[1][pt], 0, 0, 0);
            }
        }
        __builtin_amdgcn_s_setprio(0);
    };

    u32x4 LA[4], LB[4];
    short8 A[8];

    // prologue of main pipeline
    computeBase(0, 0);
    block_sync_lds();
    {
        int rb0[4];
        loadBases(0, rb0);
        issueC(rb0, 0, LA);
        issueC(rb0, 1, LB);
    }

    int p = 0;
    #pragma unroll 1
    for (int tap = 0; tap < 9; ++tap) {
        float wcur[4];
        *(float4*)&wcur[0] = *(const float4*)&sWgt[tap & 1][rq][0];
        if (tap < 8) computeBase(tap + 1, (tap + 1) & 1);

        int rb[4];
        // ---- sub 0 ----
        loadA8(tap * 8, A);                             // issue early: hides under blend+barrier
        blendDirect(LA, wcur, p);
        block_sync_lds();                               // sS[p] + next bases visible
        if (tap < 8) { loadBases((tap + 1) & 1, rb); issueC(rb, 0, LA); }
        mfmaPhase(A, p);
        p ^= 1;
        // ---- sub 1 ----
        loadA8(tap * 8 + 4, A);
        blendDirect(LB, wcur, p);
        block_sync_lds();
        if (tap < 8) issueC(rb, 1, LB);
        mfmaPhase(A, p);
        p ^= 1;
    }

    // epilogue: D[row=(l>>4)*4+j][col=l&15]
    #pragma unroll
    for (int ot = 0; ot < 2; ++ot) {
        int o = wv * 32 + ot * 16 + (lane >> 4) * 4;
        #pragma unroll
        for (int pt = 0; pt < 2; ++pt) {
            int pxx = pxh * 32 + pt * 16 + (lane & 15);
            #pragma unroll
            for (int j = 0; j < 4; ++j)
                out[(((size_t)b * OCH + (o + j)) * H + ho) * W + pxx] = acc2[ot][pt][j];
        }
    }
}

// ---------------------------------------------------------------------------
extern "C" void kernel_launch(void* const* d_in, const int* in_sizes, int n_in,
                              void* d_out, int out_size, void* d_ws, size_t ws_size,
                              hipStream_t stream)
{
    const float* x     = (const float*)d_in[0];
    const float* w_off = (const float*)d_in[1];
    const float* w_def = (const float*)d_in[2];
    float* out = (float*)d_out;

    // ws: xt01[4.19MB] | wPack[1.18MB] | wOffA[147KB] = 5.52 MB (< proven 6.7).
    // xt23 lives in d_out's batch-0 region: written by prep, read by
    // deform(pbase=2) (writes out[b2,b3] only), then overwritten by
    // deform(pbase=0)'s out[b0] stores.
    ushort_t* xt01  = (ushort_t*)d_ws;
    ushort_t* wPack = xt01 + (size_t)2 * HW * C;
    ushort_t* wOffA = wPack + (size_t)NHS * 16 * 64 * 8;
    ushort_t* xtD   = (ushort_t*)d_out;   // batch 2,3 xt scratch

    prep_all<<<1348, 256, 0, stream>>>(x, w_def, w_off, xt01, xtD, wPack, wOffA);
    deform_pair<<<256, 512, 0, stream>>>(xtD, wOffA, wPack, out, 2);
    deform_pair<<<256, 512, 0, stream>>>(xt01, wOffA, wPack, out, 0);
}

// Round 20
// 64.873 us; speedup vs baseline: 2.1551x; 1.0244x over previous
//
#include <hip/hip_runtime.h>

typedef __attribute__((ext_vector_type(8))) short short8;
typedef __attribute__((ext_vector_type(4))) float f32x4;
typedef __attribute__((ext_vector_type(4))) unsigned int u32x4;
typedef unsigned short ushort_t;

constexpr int B   = 4;
constexpr int C   = 256;
constexpr int H   = 64;
constexpr int W   = 64;
constexpr int HW  = H * W;          // 4096
constexpr int OCH = 256;
constexpr int KT  = 9 * C;          // 2304, k order: k = tap*256 + c
constexpr int NHS = KT / 32;        // 72 half-steps (MFMA K=32)

__device__ __forceinline__ ushort_t f2bf(float f) {
    unsigned u = __float_as_uint(f);
    u += 0x7FFF + ((u >> 16) & 1);      // RNE
    return (ushort_t)(u >> 16);
}

// Barrier that does NOT drain vmcnt: LDS writes are made visible
// (lgkmcnt(0)), but in-register global loads stay in flight across it.
__device__ __forceinline__ void block_sync_lds() {
    asm volatile("s_waitcnt lgkmcnt(0)" ::: "memory");
    __builtin_amdgcn_s_barrier();
    asm volatile("" ::: "memory");
}

// ---------------------------------------------------------------------------
// K0: prep = transpose (blocks 0..1023) + weight packing (blocks 1024..1347).
// Transpose: xt[b][y][x][c] (bf16) <- x[b][c][y][x] (f32); b<2 -> xt01 (ws),
// b>=2 -> xtD (d_out batch-0 scratch).  Pack: validated rounds 2-19.
// ---------------------------------------------------------------------------
__global__ __launch_bounds__(256) void prep_all(
    const float* __restrict__ x, const float* __restrict__ w_def,
    const float* __restrict__ w_off, ushort_t* __restrict__ xt01,
    ushort_t* __restrict__ xtD, ushort_t* __restrict__ wPack,
    ushort_t* __restrict__ wOffA)
{
    __shared__ float sT[64][65];
    int blk = blockIdx.x;
    if (blk < 1024) {
        int cg  = blk & 3;               // channel group of 64
        int y   = (blk >> 2) & 63;
        int b   = blk >> 8;              // 0..3
        int t   = threadIdx.x;
        int col = t & 63, r4 = t >> 6;

        const float* xp = x + (((size_t)b * C + cg * 64) * H + y) * W;
        #pragma unroll
        for (int i = 0; i < 16; ++i) {
            int cl = i * 4 + r4;
            sT[cl][col] = xp[(size_t)cl * HW + col];
        }
        __syncthreads();
        ushort_t* base = (b < 2) ? (xt01 + (size_t)b * HW * C)
                                 : (xtD + (size_t)(b - 2) * HW * C);
        ushort_t* op = base + ((size_t)y * W) * C + cg * 64;
        #pragma unroll
        for (int i = 0; i < 16; ++i) {
            int xl = i * 4 + r4;
            op[(size_t)xl * C + col] = f2bf(sT[col][xl]);
        }
    } else {
        int tid = (blk - 1024) * 256 + threadIdx.x;   // [0, 82944)
        if (tid < NHS * 16 * 64) {
            int lane = tid & 63;
            int o = ((tid >> 6) & 15) * 16 + (lane & 15);
            int kbase = (tid >> 10) * 32 + (lane >> 4) * 8;
            union { ushort_t u[8]; short8 v; } pk;
            #pragma unroll
            for (int j = 0; j < 8; ++j) {
                int kidx = kbase + j;
                int c = kidx & 255, tap = kidx >> 8;
                pk.u[j] = f2bf(w_def[((size_t)o * C + c) * 9 + tap]);
            }
            *(short8*)(wPack + (size_t)tid * 8) = pk.v;
        } else {
            int t2 = tid - NHS * 16 * 64;             // [0, 9216)
            int lane = t2 & 63;
            int o = ((t2 >> 6) & 1) * 16 + (lane & 15);
            int kbase = (t2 >> 7) * 32 + (lane >> 4) * 8;
            union { ushort_t u[8]; short8 v; } pk;
            #pragma unroll
            for (int j = 0; j < 8; ++j) {
                int kidx = kbase + j;
                int c = kidx & 255, tap = kidx >> 8;
                pk.u[j] = (o < 18) ? f2bf(w_off[((size_t)o * C + c) * 9 + tap]) : (ushort_t)0;
            }
            *(short8*)(wOffA + (size_t)t2 * 8) = pk.v;
        }
    }
}

// ---------------------------------------------------------------------------
// K4: FUSED {offset-conv MFMA prologue + bilinear sample + bf16 MFMA GEMM}.
// r19 structure with ONE change: one barrier per TAP (9 total, was 18).
// Both 128-channel subs are staged per phase (blendBoth -> 32 LDS slots);
// the MFMA phase runs 32 MFMAs in two halves with the A[8] batch reloaded
// between halves (early-issued before blend for half 0; after half-0 MFMAs
// for half 1, covered by the MFMA pipe).  Register audit: LA+LB(32) +
// A[8](32) + acc(16) + misc(~25) ~= 105 < 128 cap -> no spill (r14's spill
// was A0[16]+A1[16]=128).  Accumulation order identical to r19.
// Grid (bl,ho,pxh) = 256 blocks/launch, 512 thr, launch_bounds(512,2).
// ---------------------------------------------------------------------------
__global__ __launch_bounds__(512, 2) void deform_pair(
    const ushort_t* __restrict__ xtB, const ushort_t* __restrict__ wOffA,
    const ushort_t* __restrict__ wPack, float* __restrict__ out, int pbase)
{
    __shared__ __align__(16) ushort_t sS[2][32][33][8];  // 33.8 KB (32 slots)
    __shared__ float sOff[18][32];                       // 2.3 KB
    __shared__ float sPart[8][18][32];                   // 18.4 KB (prologue)
    __shared__ int   sBase[2][128];                      // run bases (dbuf)
    __shared__ float sWgt[2][32][4];                     // per-px nbr weights

    int orig = blockIdx.x;
    int r = ((orig & 7) << 5) | (orig >> 3);   // XCD swizzle, 256 blocks
    int bl = r >> 7, ho = (r >> 1) & 63, pxh = r & 1;
    int tid = threadIdx.x;
    int lane = tid & 63, wv = tid >> 6;        // 8 waves
    int chunk = tid & 15, rq = (tid >> 4) & 31;  // staging: pixel rq, chunk

    const ushort_t* xtb = xtB + (size_t)bl * HW * C;
    int b = pbase + bl;

    // ---------------- offset-conv prologue (split-K MFMA) ----------------
    {
        const short8* wA = (const short8*)wOffA;
        f32x4 pacc[2][2];
        #pragma unroll
        for (int i = 0; i < 2; ++i)
            #pragma unroll
            for (int j = 0; j < 2; ++j) pacc[i][j] = (f32x4){0.f, 0.f, 0.f, 0.f};

        #pragma unroll 1
        for (int i = 0; i < 9; ++i) {
            int ks = wv * 9 + i;               // this wave's K-step
            int tap = ks >> 3, cs = ks & 7;
            int ky = tap / 3, kx = tap - ky * 3;
            int y  = ho - 1 + ky;
            int yc = min(max(y, 0), 63);
            bool yok = ((unsigned)y < 64u);
            short8 a0 = wA[(size_t)ks * 128 + lane];
            short8 a1 = wA[(size_t)ks * 128 + 64 + lane];
            #pragma unroll
            for (int pt = 0; pt < 2; ++pt) {
                int px = pxh * 32 + pt * 16 + (lane & 15);
                int xx = px - 1 + kx;
                bool ok = yok && ((unsigned)xx < 64u);
                unsigned msk = ok ? 0xffffffffu : 0u;
                int xc = min(max(xx, 0), 63);
                const ushort_t* srcb = xtb + (size_t)(yc * 64 + xc) * C
                                       + cs * 32 + (lane >> 4) * 8;
                union { u32x4 u; short8 s; } bv;
                bv.u = *(const u32x4*)srcb;
                bv.u[0] &= msk; bv.u[1] &= msk; bv.u[2] &= msk; bv.u[3] &= msk;
                pacc[0][pt] = __builtin_amdgcn_mfma_f32_16x16x32_bf16(a0, bv.s, pacc[0][pt], 0, 0, 0);
                pacc[1][pt] = __builtin_amdgcn_mfma_f32_16x16x32_bf16(a1, bv.s, pacc[1][pt], 0, 0, 0);
            }
        }
        // write partials (D: row=(l>>4)*4+j, col=l&15), only oc<18
        #pragma unroll
        for (int gt = 0; gt < 2; ++gt) {
            #pragma unroll
            for (int pt = 0; pt < 2; ++pt) {
                #pragma unroll
                for (int j = 0; j < 4; ++j) {
                    int oc = gt * 16 + (lane >> 4) * 4 + j;
                    if (oc < 18)
                        sPart[wv][oc][pt * 16 + (lane & 15)] = pacc[gt][pt][j];
                }
            }
        }
    }
    __syncthreads();
    for (int idx = tid; idx < 18 * 32; idx += 512) {
        int oc = idx >> 5, q = idx & 31;
        float s = 0.f;
        #pragma unroll
        for (int g = 0; g < 8; ++g) s += sPart[g][oc][q];
        sOff[oc][q] = s;
    }
    __syncthreads();

    // ---------------- main loop ----------------
    f32x4 acc2[2][2];
    #pragma unroll
    for (int i = 0; i < 2; ++i)
        #pragma unroll
        for (int j = 0; j < 2; ++j) acc2[i][j] = (f32x4){0.f, 0.f, 0.f, 0.f};

    // run bases + per-pixel neighbor weights (validity folded in), dbuf by tap
    auto computeBase = [&](int tap, int buf) {
        if (tid < 128) {
            int n = tid >> 5, q = tid & 31;
            int ky = tap / 3, kx = tap - ky * 3;
            float offy = sOff[2 * tap][q];
            float offx = sOff[2 * tap + 1][q];
            float py  = offy + (float)(ho - 1 + ky);
            float pxf = offx + (float)(pxh * 32 + q - 1 + kx);
            float y0f = floorf(py), x0f = floorf(pxf);
            float wy1 = py - y0f, wx1 = pxf - x0f;
            int y0 = (int)y0f, x0 = (int)x0f;
            int dy = n >> 1, dx = n & 1;
            int yy = y0 + dy, xx = x0 + dx;
            float wn = (dy ? wy1 : (1.f - wy1)) * (dx ? wx1 : (1.f - wx1));
            wn *= (((unsigned)yy < 64u) ? 1.f : 0.f) * (((unsigned)xx < 64u) ? 1.f : 0.f);
            int yc = min(max(yy, 0), 63), xc = min(max(xx, 0), 63);
            sBase[buf][tid] = (yc * 64 + xc) * C;
            sWgt[buf][q][n] = wn;
        }
    };

    auto loadBases = [&](int buf, int* rb) {
        #pragma unroll
        for (int n = 0; n < 4; ++n) rb[n] = sBase[buf][n * 32 + rq];
    };

    // coalesced: 8 x 16B, neighbor n of pixel rq, both subs
    auto issueBoth = [&](const int* rb, u32x4* La, u32x4* Lb) {
        #pragma unroll
        for (int n = 0; n < 4; ++n) {
            const ushort_t* p0 = xtb + rb[n] + chunk * 8;
            La[n] = *(const u32x4*)p0;
            Lb[n] = *(const u32x4*)(p0 + 128);
        }
    };

    // in-register blend: one pixel (rq), 4 neighbors -> one sS slot
    auto blendOne = [&](const u32x4* L, const float* w, int p, int slot) {
        unsigned pk[4];
        #pragma unroll
        for (int j = 0; j < 4; ++j) {
            float f0l = __uint_as_float(L[0][j] << 16);
            float f0h = __uint_as_float(L[0][j] & 0xffff0000u);
            float f1l = __uint_as_float(L[1][j] << 16);
            float f1h = __uint_as_float(L[1][j] & 0xffff0000u);
            float f2l = __uint_as_float(L[2][j] << 16);
            float f2h = __uint_as_float(L[2][j] & 0xffff0000u);
            float f3l = __uint_as_float(L[3][j] << 16);
            float f3h = __uint_as_float(L[3][j] & 0xffff0000u);
            float lo = fmaf(w[0], f0l, fmaf(w[1], f1l, fmaf(w[2], f2l, w[3] * f3l)));
            float hi = fmaf(w[0], f0h, fmaf(w[1], f1h, fmaf(w[2], f2h, w[3] * f3h)));
            asm("v_cvt_pk_bf16_f32 %0, %1, %2" : "=v"(pk[j]) : "v"(lo), "v"(hi));
        }
        u32x4 wvec = (u32x4){pk[0], pk[1], pk[2], pk[3]};
        *(u32x4*)&sS[p][slot][rq][0] = wvec;
    };

    int gt0 = wv * 2;
    const short8* wpB = (const short8*)wPack;

    // batch-issue the 8 A-fragments of one sub
    auto loadA8 = [&](int ks4base, short8* A) {
        #pragma unroll
        for (int h = 0; h < 4; ++h) {
            size_t an = ((size_t)(ks4base + h) * 16 + gt0) * 64 + lane;
            A[2 * h]     = wpB[an];
            A[2 * h + 1] = wpB[an + 64];
        }
    };

    auto mfmaHalf = [&](const short8* A, int p, int half) {
        __builtin_amdgcn_s_setprio(1);            // T5: favor MFMA wave
        #pragma unroll
        for (int h = 0; h < 4; ++h) {
            #pragma unroll
            for (int pt = 0; pt < 2; ++pt) {
                short8 bF = *(const short8*)&sS[p][half * 16 + h * 4 + (lane >> 4)][pt * 16 + (lane & 15)][0];
                acc2[0][pt] = __builtin_amdgcn_mfma_f32_16x16x32_bf16(A[2 * h],     bF, acc2[0][pt], 0, 0, 0);
                acc2[1][pt] = __builtin_amdgcn_mfma_f32_16x16x32_bf16(A[2 * h + 1], bF, acc2[1][pt], 0, 0, 0);
            }
        }
        __builtin_amdgcn_s_setprio(0);
    };

    u32x4 LA[4], LB[4];
    short8 A[8];

    // prologue of main pipeline
    computeBase(0, 0);
    block_sync_lds();
    {
        int rb0[4];
        loadBases(0, rb0);
        issueBoth(rb0, LA, LB);
    }

    int p = 0;
    #pragma unroll 1
    for (int tap = 0; tap < 9; ++tap) {
        float wcur[4];
        *(float4*)&wcur[0] = *(const float4*)&sWgt[tap & 1][rq][0];
        if (tap < 8) computeBase(tap + 1, (tap + 1) & 1);

        loadA8(tap * 8, A);                 // half-0 A: hides under blend+barrier
        blendOne(LA, wcur, p, chunk);       // sub0 -> slots 0..15
        blendOne(LB, wcur, p, 16 + chunk);  // sub1 -> slots 16..31
        block_sync_lds();                   // ONE barrier per tap

        int rb[4];
        if (tap < 8) { loadBases((tap + 1) & 1, rb); issueBoth(rb, LA, LB); }

        mfmaHalf(A, p, 0);                  // sub0: 16 MFMA
        loadA8(tap * 8 + 4, A);             // half-1 A: covered by MFMA pipe
        mfmaHalf(A, p, 1);                  // sub1: 16 MFMA
        p ^= 1;
    }

    // epilogue: D[row=(l>>4)*4+j][col=l&15]
    #pragma unroll
    for (int ot = 0; ot < 2; ++ot) {
        int o = wv * 32 + ot * 16 + (lane >> 4) * 4;
        #pragma unroll
        for (int pt = 0; pt < 2; ++pt) {
            int pxx = pxh * 32 + pt * 16 + (lane & 15);
            #pragma unroll
            for (int j = 0; j < 4; ++j)
                out[(((size_t)b * OCH + (o + j)) * H + ho) * W + pxx] = acc2[ot][pt][j];
        }
    }
}

// ---------------------------------------------------------------------------
extern "C" void kernel_launch(void* const* d_in, const int* in_sizes, int n_in,
                              void* d_out, int out_size, void* d_ws, size_t ws_size,
                              hipStream_t stream)
{
    const float* x     = (const float*)d_in[0];
    const float* w_off = (const float*)d_in[1];
    const float* w_def = (const float*)d_in[2];
    float* out = (float*)d_out;

    // ws: xt01[4.19MB] | wPack[1.18MB] | wOffA[147KB] = 5.52 MB (< proven 6.7).
    // xt23 lives in d_out's batch-0 region: written by prep, read by
    // deform(pbase=2) (writes out[b2,b3] only), then overwritten by
    // deform(pbase=0)'s out[b0] stores.
    ushort_t* xt01  = (ushort_t*)d_ws;
    ushort_t* wPack = xt01 + (size_t)2 * HW * C;
    ushort_t* wOffA = wPack + (size_t)NHS * 16 * 64 * 8;
    ushort_t* xtD   = (ushort_t*)d_out;   // batch 2,3 xt scratch

    prep_all<<<1348, 256, 0, stream>>>(x, w_def, w_off, xt01, xtD, wPack, wOffA);
    deform_pair<<<256, 512, 0, stream>>>(xtD, wOffA, wPack, out, 2);
    deform_pair<<<256, 512, 0, stream>>>(xt01, wOffA, wPack, out, 0);
}